// Round 1
// baseline (1892.720 us; speedup 1.0000x reference)
//
#include <hip/hip_runtime.h>
#include <hip/hip_bf16.h>
#include <cstdint>

// Problem constants: B=8, D=512, T=2048, K=8192. BT = 16384 queries.
constexpr int Dv = 512;
constexpr int Tv = 2048;
constexpr int Kv = 8192;
constexpr int BT = 16384;

constexpr int BQ = 128;   // queries per block tile
constexpr int BK = 128;   // codes per block tile
constexpr int BD = 64;    // d-chunk
constexpr int KSPL = 4;   // K split across blocks
constexpr int KPS = Kv / KSPL;   // 2048 codes per split

// ---------------------------------------------------------------- x_sq ----
__global__ void vq_xsq(const float* __restrict__ lat, float* __restrict__ xsq) {
    int q = blockIdx.x * 256 + threadIdx.x;      // 64 blocks x 256 = 16384
    int b = q >> 11, t = q & 2047;
    const float* p = lat + (size_t)b * Dv * Tv + t;
    float a = 0.f;
    #pragma unroll 8
    for (int d = 0; d < Dv; ++d) {
        float v = p[(size_t)d * Tv];
        a = fmaf(v, v, a);
    }
    xsq[q] = a;
}

// ---------------------------------------------------------------- e_sq ----
__global__ void vq_esq(const float* __restrict__ emb, float* __restrict__ esq) {
    int gid = blockIdx.x * 256 + threadIdx.x;
    int k = gid >> 6;                 // one wave per code row; 2048 blocks
    int l = threadIdx.x & 63;
    const float* p = emb + (size_t)k * Dv + l;
    float a = 0.f;
    #pragma unroll
    for (int i = 0; i < 8; ++i) {
        float v = p[i * 64];
        a = fmaf(v, v, a);
    }
    #pragma unroll
    for (int off = 32; off; off >>= 1) a += __shfl_down(a, off, 64);
    if (l == 0) esq[k] = a;
}

// ----------------------------------------------------------------- main ---
// grid 512 = 128 q-blocks x 4 k-splits, 256 threads, 2 blocks/CU.
__global__ __launch_bounds__(256, 2) void vq_main(
        const float* __restrict__ lat, const float* __restrict__ emb,
        const float* __restrict__ xsq, const float* __restrict__ esq,
        float* __restrict__ pval, int* __restrict__ pidx) {
    __shared__ float Xs[BD][BQ];        // [dd][q]   32 KB, rows 512B
    __shared__ float Es[BD][BK + 4];    // [dd][kk]  33 KB, rows 528B (16B-aligned)

    const int tid = threadIdx.x;
    const int bid = blockIdx.x;
    const int qb = bid & 127;
    const int ks = bid >> 7;
    const int q0 = qb * BQ;
    const int b  = q0 >> 11;
    const int t0 = q0 & 2047;
    const int k0base = ks * KPS;

    // lane remap: within a wave both tx and ty span 8 values -> all inner-loop
    // LDS b128 reads are 8 distinct 32B addrs = 2-way bank aliasing (free).
    const int tx = (tid & 7) | (((tid >> 6) & 1) << 3);       // [0,16) k dim
    const int ty = ((tid >> 3) & 7) | (((tid >> 7) & 1) << 3); // [0,16) q dim

    // staging maps (independent of tx/ty)
    const int sq   = tid & 31;   // X: 32 float4 lanes per row
    const int srow = tid >> 5;   // X: 8 row groups
    const int ef   = tid & 15;   // E: 16 float4 per 64-wide d-row
    const int ekk  = tid >> 4;   // E: 16 row groups

    float best[8];
    int   bidx[8];
    float xs[8];
    #pragma unroll
    for (int i = 0; i < 8; ++i) {
        best[i] = 3.4e38f;
        bidx[i] = 0x7fffffff;
        xs[i] = xsq[q0 + ty * 8 + i];
    }

    const float* latb = lat + (size_t)b * Dv * Tv + t0;

    for (int kc = 0; kc < KPS / BK; ++kc) {
        const int k0 = k0base + kc * BK;
        float c[8][8];
        #pragma unroll
        for (int i = 0; i < 8; ++i)
            #pragma unroll
            for (int j = 0; j < 8; ++j) c[i][j] = 0.f;

        for (int dc = 0; dc < Dv / BD; ++dc) {
            const int d0 = dc * BD;
            __syncthreads();
            // stage X tile: Xs[dd][q] = lat[b][d0+dd][t0+q]  (no transpose needed)
            #pragma unroll
            for (int i = 0; i < 8; ++i) {
                int dd = srow + i * 8;
                float4 v = *(const float4*)(latb + (size_t)(d0 + dd) * Tv + sq * 4);
                *(float4*)&Xs[dd][sq * 4] = v;
            }
            // stage E tile transposed: Es[dd][kk] = emb[k0+kk][d0+dd]
            #pragma unroll
            for (int i = 0; i < 8; ++i) {
                int kk = ekk + i * 16;
                float4 v = *(const float4*)(emb + (size_t)(k0 + kk) * Dv + d0 + ef * 4);
                Es[ef * 4 + 0][kk] = v.x;
                Es[ef * 4 + 1][kk] = v.y;
                Es[ef * 4 + 2][kk] = v.z;
                Es[ef * 4 + 3][kk] = v.w;
            }
            __syncthreads();

            // accumulate: STRICTLY sequential fp32 fma chain over d (matches
            // BLAS sgemm accumulation order -> matches np reference rounding)
            #pragma unroll 4
            for (int dd = 0; dd < BD; ++dd) {
                float4 xa = *(const float4*)&Xs[dd][ty * 8];
                float4 xb = *(const float4*)&Xs[dd][ty * 8 + 4];
                float4 ea = *(const float4*)&Es[dd][tx * 8];
                float4 eb = *(const float4*)&Es[dd][tx * 8 + 4];
                float x8[8] = {xa.x, xa.y, xa.z, xa.w, xb.x, xb.y, xb.z, xb.w};
                float e8[8] = {ea.x, ea.y, ea.z, ea.w, eb.x, eb.y, eb.z, eb.w};
                #pragma unroll
                for (int i = 0; i < 8; ++i)
                    #pragma unroll
                    for (int j = 0; j < 8; ++j)
                        c[i][j] = fmaf(x8[i], e8[j], c[i][j]);
            }
        }

        // distances + running argmin for this k-chunk.
        // dist = fl(fl(x_sq - 2c) + e_sq): fmaf(-2,c,xs) is bit-identical to
        // the reference's x_sq - (2*c) since 2c is exact.
        float es8[8];
        #pragma unroll
        for (int j = 0; j < 8; ++j) es8[j] = esq[k0 + tx * 8 + j];
        #pragma unroll
        for (int i = 0; i < 8; ++i)
            #pragma unroll
            for (int j = 0; j < 8; ++j) {
                float dist = fmaf(-2.0f, c[i][j], xs[i]) + es8[j];
                int kk = k0 + tx * 8 + j;
                if (dist < best[i]) { best[i] = dist; bidx[i] = kk; }  // strict < : first index wins
            }
    }

    // cross-tx reduction via LDS (reuse tiles as scratch)
    __syncthreads();
    float* redv = &Xs[0][0];         // 256*8 floats
    int*   redi = (int*)&Es[0][0];
    #pragma unroll
    for (int i = 0; i < 8; ++i) {
        redv[(ty * 16 + tx) * 8 + i] = best[i];
        redi[(ty * 16 + tx) * 8 + i] = bidx[i];
    }
    __syncthreads();
    if (tid < 128) {
        int yy = tid >> 3, ii = tid & 7;
        float bv = 3.4e38f;
        int bi = 0x7fffffff;
        #pragma unroll
        for (int t = 0; t < 16; ++t) {
            float v = redv[(yy * 16 + t) * 8 + ii];
            int  ix = redi[(yy * 16 + t) * 8 + ii];
            if (v < bv || (v == bv && ix < bi)) { bv = v; bi = ix; }
        }
        int q = q0 + yy * 8 + ii;
        pval[(size_t)q * KSPL + ks] = bv;
        pidx[(size_t)q * KSPL + ks] = bi;
    }
}

// ---------------------------------------------------------------- merge ---
__global__ void vq_merge(const float* __restrict__ pval, const int* __restrict__ pidx,
                         int* __restrict__ idxf) {
    int q = blockIdx.x * 256 + threadIdx.x;    // 64 blocks
    float bv = 3.4e38f;
    int bi = 0x7fffffff;
    #pragma unroll
    for (int s = 0; s < KSPL; ++s) {
        float v = pval[(size_t)q * KSPL + s];
        int  ix = pidx[(size_t)q * KSPL + s];
        if (v < bv || (v == bv && ix < bi)) { bv = v; bi = ix; }
    }
    idxf[q] = bi;
}

// --------------------------------------------------------------- gather ---
// out[b][d][t] = emb[idx[b*T+t]][d]; lanes along t -> coalesced stores.
__global__ void vq_gather(const float* __restrict__ emb, const int* __restrict__ idxf,
                          float* __restrict__ out) {
    int blk = blockIdx.x;            // 256 blocks of 64 queries
    int tid = threadIdx.x;
    int tl = tid & 63, dg = tid >> 6;   // dg in [0,4)
    int q = blk * 64 + tl;
    int b = q >> 11, t = q & 2047;
    int idx = idxf[q];
    const float* er = emb + (size_t)idx * Dv + dg * 128;
    float* ob = out + ((size_t)b * Dv + dg * 128) * Tv + t;
    #pragma unroll 8
    for (int i = 0; i < 128; ++i) ob[(size_t)i * Tv] = er[i];
}

// ---------------------------------------------------------------------------
extern "C" void kernel_launch(void* const* d_in, const int* in_sizes, int n_in,
                              void* d_out, int out_size, void* d_ws, size_t ws_size,
                              hipStream_t stream) {
    (void)in_sizes; (void)n_in; (void)out_size; (void)ws_size;
    const float* lat = (const float*)d_in[0];   // [8, 512, 2048]
    const float* emb = (const float*)d_in[1];   // [8192, 512]
    float* out = (float*)d_out;                 // [8, 512, 2048]

    char* ws = (char*)d_ws;
    float* xsq  = (float*)(ws);                                  // 64 KB
    float* esq  = (float*)(ws + (64 << 10));                     // 32 KB
    float* pval = (float*)(ws + (96 << 10));                     // 256 KB
    int*   pidx = (int*)  (ws + (96 << 10) + (256 << 10));       // 256 KB
    int*   idxf = (int*)  (ws + (96 << 10) + (512 << 10));       // 64 KB

    vq_xsq  <<<BT / 256, 256, 0, stream>>>(lat, xsq);
    vq_esq  <<<Kv / 4,   256, 0, stream>>>(emb, esq);
    vq_main <<<(BT / BQ) * KSPL, 256, 0, stream>>>(lat, emb, xsq, esq, pval, pidx);
    vq_merge<<<BT / 256, 256, 0, stream>>>(pval, pidx, idxf);
    vq_gather<<<BT / 64, 256, 0, stream>>>(emb, idxf, out);
}